// Round 4
// baseline (425.673 us; speedup 1.0000x reference)
//
#include <hip/hip_runtime.h>
#include <hip/hip_fp16.h>

// Problem constants
#define B_     8
#define NCAM   5
#define J_     15
#define H_     128
#define W_     240
#define NB     128000             // bins = 80*80*20
#define HW_    (H_ * W_)          // 30720
// Overlapping row-pair f16 image: dword[y][x] = (f16 v(y,x), f16 v(y+1,x)),
// y in 0..H-2. Any clamped 2x2 window = dwords (yc,xc),(yc,xc+1): ONE
// ds_read2_b32 per sample, all 8B useful.
#define OV_ROWS (H_ - 1)          // 127
#define OV_DW   (OV_ROWS * W_)    // 30480 dwords
#define SMEM_BYTES (OV_DW * 4)    // 121920 B -> 1 block/CU (16 waves)
#define OV_G4   (OV_DW / 4)       // 7620 uint4 groups
#define TPB    1024
#define NCHUNK 4                  // 480 blocks
#define BPB    (NB / NCHUNK)      // 32000 bins per block
#define ITEMS  32                 // 32000/1024 = 31.25; last item partial
#define NBJ    (B_ * J_)          // 120
#define NBLK   (NBJ * NCHUNK)     // 480
// R4: R2/R3 post-mortem — batch arrays went to scratch (SROA runs BEFORE
// unroll; runtime-indexed locals are demoted, rule #20), and dynamic LDS hid
// the real occupancy (compiler targeted 8 waves/EU -> 64-VGPR cap).
// Fixes: (1) STATIC __shared__ so backend knows 1 block/CU = 4 waves/EU ->
// honest ~128 VGPR budget; (2) straight-line macro SSA pipeline, every
// index a literal, no loops around register arrays, no rotation.

typedef __fp16 fp16x2 __attribute__((ext_vector_type(2)));

__device__ __forceinline__ unsigned int pkrtz(float lo, float hi) {
    fp16x2 h = __builtin_amdgcn_cvt_pkrtz(lo, hi);  // v_cvt_pkrtz_f16_f32
    return __builtin_bit_cast(unsigned int, h);
}

// f32 dot of two f16 pairs: v_dot2_f32_f16 (f32 accumulate, more precise
// than an hmul2/hfma2 chain which rounds products to f16).
__device__ __forceinline__ float fdot2(unsigned int d, unsigned int w, float c) {
#if __has_builtin(__builtin_amdgcn_fdot2)
    return __builtin_amdgcn_fdot2(__builtin_bit_cast(fp16x2, d),
                                  __builtin_bit_cast(fp16x2, w), c, false);
#else
    __half2 p = __hmul2(__builtin_bit_cast(__half2, d),
                        __builtin_bit_cast(__half2, w));
    return c + __low2float(p) + __high2float(p);
#endif
}

// Bilinear weights, padding_mode='zeros' validity folded into clamped 2x2
// window. Camera-mean 1/5 folded into weights.
// addr16 = yc*W + xc (max 30478, fits u16);
// w0pk=(0.2*a0*b0, 0.2*a0*b1) for col xc, w1pk likewise for xc+1 — pair over
// rows (yc, yc+1) matches the overlapping row-pair LDS dword layout.
__device__ __forceinline__ void bilinear_rec(float gx, float gy,
                                             unsigned int& addr,
                                             unsigned int& w0pk,
                                             unsigned int& w1pk) {
    const float ix = (gx + 1.0f) * (0.5f * (W_ - 1));
    const float iy = (gy + 1.0f) * (0.5f * (H_ - 1));
    const float x0f = floorf(ix);
    const float y0f = floorf(iy);
    const float wx1 = ix - x0f, wx0 = 1.0f - wx1;
    const float wy1 = iy - y0f, wy0 = 1.0f - wy1;
    const int x0 = (int)x0f;
    const int y0 = (int)y0f;
    const int xc = min(max(x0, 0), W_ - 2);
    const int yc = min(max(y0, 0), H_ - 2);
    const float vx0 = (x0 >= 0  && x0 <= W_ - 1) ? wx0 : 0.0f;
    const float vx1 = (x0 >= -1 && x0 <= W_ - 2) ? wx1 : 0.0f;
    const float vy0 = (y0 >= 0  && y0 <= H_ - 1) ? wy0 : 0.0f;
    const float vy1 = (y0 >= -1 && y0 <= H_ - 2) ? wy1 : 0.0f;
    const bool xhi = (x0 == W_ - 1);
    const bool xlo = (x0 == -1);
    const bool yhi = (y0 == H_ - 1);
    const bool ylo = (y0 == -1);
    const float a0 = (xhi ? 0.0f : vx0) + (xlo ? vx1 : 0.0f);
    const float a1 = (xhi ? vx0 : 0.0f) + (xlo ? 0.0f : vx1);
    const float b0 = (yhi ? 0.0f : vy0) + (ylo ? vy1 : 0.0f);
    const float b1 = (yhi ? vy0 : 0.0f) + (ylo ? 0.0f : vy1);
    addr = (unsigned int)(yc * W_ + xc);
    w0pk = pkrtz(0.2f * (a0 * b0), 0.2f * (a0 * b1));
    w1pk = pkrtz(0.2f * (a1 * b0), 0.2f * (a1 * b1));
}

__global__ __launch_bounds__(256) void weights_kernel(
    const float* __restrict__ sgrid,          // [NCAM, NB, 2]
    unsigned short* __restrict__ addr16,      // [NCAM*NB]
    uint2* __restrict__ wpk)                  // [NCAM*NB]
{
    const int i = blockIdx.x * 256 + threadIdx.x;
    if (i >= NCAM * NB) return;
    const float2 g = ((const float2*)sgrid)[i];
    unsigned int a, w0, w1;
    bilinear_rec(g.x, g.y, a, w0, w1);
    addr16[i] = (unsigned short)a;
    wpk[i] = make_uint2(w0, w1);
}

// Stage f32 HxW image as overlapping row-pair f16 dwords (121.9 KB).
__device__ __forceinline__ void stage_overlap(const float* __restrict__ img,
                                              unsigned int* s_img, int tid) {
    const float4* __restrict__ src4 = (const float4*)img;  // 60 groups per row
    uint4* dst = (uint4*)s_img;
    for (int gi = tid; gi < OV_G4; gi += TPB) {
        const int y  = gi / 60;
        const int xg = gi - y * 60;
        const float4 t = src4[y * 60 + xg];        // row y
        const float4 b = src4[y * 60 + 60 + xg];   // row y+1
        uint4 d;
        d.x = pkrtz(t.x, b.x);
        d.y = pkrtz(t.y, b.y);
        d.z = pkrtz(t.z, b.z);
        d.w = pkrtz(t.w, b.w);
        dst[gi] = d;
    }
}

// ---- straight-line SSA pipeline macros (all indices literal) ----
#define LOADI(G, U) \
    const unsigned int a##U##_##G = ap[((G)*4 + (U)) * TPB + tid]; \
    const uint2        w##U##_##G = wp[((G)*4 + (U)) * TPB + tid];
#define LOADB(G) LOADI(G, 0) LOADI(G, 1) LOADI(G, 2) LOADI(G, 3)
// last batch: item 31 lane-guarded (r >= BPB would read OOB of the buffers)
#define LOADB7 \
    LOADI(7, 0) LOADI(7, 1) LOADI(7, 2) \
    const unsigned int a3_7 = tail_ok ? (unsigned int)ap[31 * TPB + tid] : 0u; \
    const uint2        w3_7 = tail_ok ? wp[31 * TPB + tid] : make_uint2(0u, 0u);

#define LDSI(G, U) \
    const unsigned int p##U##_##G = s_img[a##U##_##G]; \
    const unsigned int q##U##_##G = s_img[a##U##_##G + 1u];
#define LDSB(G) LDSI(G, 0) LDSI(G, 1) LDSI(G, 2) LDSI(G, 3)

#define DOTI(G, U) \
    acc[(G)*4 + (U)] = fdot2(q##U##_##G, w##U##_##G.y, \
                       fdot2(p##U##_##G, w##U##_##G.x, acc[(G)*4 + (U)]));
#define DOTB(G) DOTI(G, 0) DOTI(G, 1) DOTI(G, 2) DOTI(G, 3)

// stage boundary: stop the scheduler hoisting ALL batches' loads at once
// (that pressure explosion is what spilled R2/R3)
#define SBAR __builtin_amdgcn_sched_barrier(0)

#define ZI(IT)  acc[IT] = 0.0f;
#define OUTI(IT) o[(IT) * TPB + tid] = fminf(fmaxf(acc[IT], 0.0f), 1.0f);

// Static LDS: backend sees 121.9 KB -> knows 1 block/CU (4 waves/EU) -> full
// register budget. 16 waves/block.
__global__ __launch_bounds__(TPB, 4) void project_kernel(
    const float* __restrict__ hm,             // [B, NCAM, J, H, W]
    const unsigned short* __restrict__ addr16,
    const uint2* __restrict__ wpk,
    float* __restrict__ out)                  // [B, J, NB]
{
    __shared__ unsigned int s_img[OV_DW];     // STATIC: 121920 B
    const int tid   = threadIdx.x;
    // bj-major mapping: same-bj blocks at bids bj+120k; 120%8==0 -> same XCD,
    // so all 4 chunks of a (b,j) share one XCD's L2 for the staged images.
    const int bj    = blockIdx.x % NBJ;
    const int chunk = blockIdx.x / NBJ;
    const int b     = bj / J_;
    const int j     = bj % J_;
    const int bin0  = chunk * BPB;
    // last item: r = 31*1024+tid < 32000  <=>  tid < 256
    const bool tail_ok = (tid < BPB - (ITEMS - 1) * TPB);

    float acc[ITEMS];
    ZI(0) ZI(1) ZI(2) ZI(3) ZI(4) ZI(5) ZI(6) ZI(7)
    ZI(8) ZI(9) ZI(10) ZI(11) ZI(12) ZI(13) ZI(14) ZI(15)
    ZI(16) ZI(17) ZI(18) ZI(19) ZI(20) ZI(21) ZI(22) ZI(23)
    ZI(24) ZI(25) ZI(26) ZI(27) ZI(28) ZI(29) ZI(30) ZI(31)

    for (int n = 0; n < NCAM; ++n) {
        const unsigned short* __restrict__ ap = addr16 + n * NB + bin0;
        const uint2* __restrict__ wp = wpk + n * NB + bin0;
        // Issue batches 0-1's weight loads early: ~500cy L3 latency hides
        // under the staging phase (they don't touch LDS).
        LOADB(0) LOADB(1)
        __syncthreads();          // prev camera's sampling done
        stage_overlap(hm + (((size_t)b * NCAM + n) * J_ + j) * HW_, s_img, tid);
        __syncthreads();
        // Software pipeline: LDS(g) | LOAD(g+2) | DOT(g-1), pure SSA.
        LDSB(0) LOADB(2)          SBAR;
        LDSB(1) LOADB(3) DOTB(0)  SBAR;
        LDSB(2) LOADB(4) DOTB(1)  SBAR;
        LDSB(3) LOADB(5) DOTB(2)  SBAR;
        LDSB(4) LOADB(6) DOTB(3)  SBAR;
        LDSB(5) LOADB7   DOTB(4)  SBAR;
        LDSB(6)          DOTB(5)  SBAR;
        LDSB(7)          DOTB(6)  SBAR;
                         DOTB(7)
    }

    float* __restrict__ o = out + (size_t)bj * NB + bin0;
    OUTI(0) OUTI(1) OUTI(2) OUTI(3) OUTI(4) OUTI(5) OUTI(6) OUTI(7)
    OUTI(8) OUTI(9) OUTI(10) OUTI(11) OUTI(12) OUTI(13) OUTI(14) OUTI(15)
    OUTI(16) OUTI(17) OUTI(18) OUTI(19) OUTI(20) OUTI(21) OUTI(22) OUTI(23)
    OUTI(24) OUTI(25) OUTI(26) OUTI(27) OUTI(28) OUTI(29) OUTI(30)
    if (tail_ok) { OUTI(31) }
}

// Fallback (tiny ws): R1-style f32-LDS kernel, inline weights. 600 blocks.
#define FB_SMEM   (HW_ * 4)
#define FB_NCHUNK 5
#define FB_BPB    (NB / FB_NCHUNK)   // 25600
#define FB_ITEMS  (FB_BPB / TPB)     // 25
__global__ __launch_bounds__(TPB) void project_fallback(
    const float* __restrict__ hm,
    const float* __restrict__ sgrid,
    float* __restrict__ out)
{
    extern __shared__ float s_f32[];
    const int tid   = threadIdx.x;
    const int bj    = blockIdx.x % NBJ;
    const int chunk = blockIdx.x / NBJ;
    const int b     = bj / J_;
    const int j     = bj % J_;
    const int bin0  = chunk * FB_BPB;

    float acc[FB_ITEMS];
#pragma unroll
    for (int it = 0; it < FB_ITEMS; ++it) acc[it] = 0.0f;

    for (int n = 0; n < NCAM; ++n) {
        __syncthreads();
        const float4* __restrict__ src =
            (const float4*)(hm + (((size_t)b * NCAM + n) * J_ + j) * HW_);
        float4* dst = (float4*)s_f32;
        for (int i = tid; i < HW_ / 4; i += TPB) dst[i] = src[i];
        __syncthreads();
        const float2* __restrict__ g2 = (const float2*)sgrid + n * NB + bin0;
#pragma unroll
        for (int it = 0; it < FB_ITEMS; ++it) {
            const float2 g = g2[it * TPB + tid];
            const float ix = (g.x + 1.0f) * (0.5f * (W_ - 1));
            const float iy = (g.y + 1.0f) * (0.5f * (H_ - 1));
            const float x0f = floorf(ix), y0f = floorf(iy);
            const float wx1 = ix - x0f, wx0 = 1.0f - wx1;
            const float wy1 = iy - y0f, wy0 = 1.0f - wy1;
            const int x0 = (int)x0f, y0 = (int)y0f;
            const int xc = min(max(x0, 0), W_ - 2);
            const int yc = min(max(y0, 0), H_ - 2);
            const float vx0 = (x0 >= 0  && x0 <= W_ - 1) ? wx0 : 0.0f;
            const float vx1 = (x0 >= -1 && x0 <= W_ - 2) ? wx1 : 0.0f;
            const float vy0 = (y0 >= 0  && y0 <= H_ - 1) ? wy0 : 0.0f;
            const float vy1 = (y0 >= -1 && y0 <= H_ - 2) ? wy1 : 0.0f;
            const bool xhi = (x0 == W_ - 1), xlo = (x0 == -1);
            const bool yhi = (y0 == H_ - 1), ylo = (y0 == -1);
            const float a0 = (xhi ? 0.0f : vx0) + (xlo ? vx1 : 0.0f);
            const float a1 = (xhi ? vx0 : 0.0f) + (xlo ? 0.0f : vx1);
            const float b0 = (yhi ? 0.0f : vy0) + (ylo ? vy1 : 0.0f);
            const float b1 = (yhi ? vy0 : 0.0f) + (ylo ? 0.0f : vy1);
            const float* r0 = s_f32 + (yc * W_ + xc);
            acc[it] += b0 * (a0 * r0[0] + a1 * r0[1])
                     + b1 * (a0 * r0[W_] + a1 * r0[W_ + 1]);
        }
    }
    float* __restrict__ o = out + (size_t)bj * NB + bin0;
#pragma unroll
    for (int it = 0; it < FB_ITEMS; ++it)
        o[it * TPB + tid] = fminf(fmaxf(acc[it] * 0.2f, 0.0f), 1.0f);
}

extern "C" void kernel_launch(void* const* d_in, const int* in_sizes, int n_in,
                              void* d_out, int out_size, void* d_ws, size_t ws_size,
                              hipStream_t stream) {
    const float* hm = (const float*)d_in[0];   // [8,5,15,128,240] f32
    const float* sg = (const float*)d_in[1];   // [5,128000,2] f32
    float* out = (float*)d_out;                // [8,15,128000] f32

    (void)hipFuncSetAttribute((const void*)project_fallback,
                              hipFuncAttributeMaxDynamicSharedMemorySize, FB_SMEM);

    const size_t addr_bytes = (size_t)NCAM * NB * sizeof(unsigned short); // 1.28 MB
    const size_t wpk_bytes  = (size_t)NCAM * NB * sizeof(uint2);          // 5.12 MB
    if (ws_size >= addr_bytes + wpk_bytes) {
        unsigned short* addr16 = (unsigned short*)d_ws;
        uint2* wpk = (uint2*)((char*)d_ws + addr_bytes);
        weights_kernel<<<(NCAM * NB + 255) / 256, 256, 0, stream>>>(sg, addr16, wpk);
        project_kernel<<<NBLK, TPB, 0, stream>>>(hm, addr16, wpk, out);
    } else {
        project_fallback<<<NBJ * FB_NCHUNK, TPB, FB_SMEM, stream>>>(hm, sg, out);
    }
}

// Round 5
// 374.896 us; speedup vs baseline: 1.1354x; 1.1354x over previous
//
#include <hip/hip_runtime.h>
#include <hip/hip_fp16.h>

// Problem constants
#define B_     8
#define NCAM   5
#define J_     15
#define H_     128
#define W_     240
#define NB     128000             // bins = 80*80*20
#define HW_    (H_ * W_)          // 30720
// Overlapping row-pair f16 image: dword[y][x] = (f16 v(y,x), f16 v(y+1,x)),
// y in 0..H-2. Any clamped 2x2 window = dwords (yc,xc),(yc,xc+1): ONE
// ds_read2_b32 per sample, all 8B useful.
#define OV_ROWS (H_ - 1)          // 127
#define OV_DW   (OV_ROWS * W_)    // 30480 dwords
#define OV_G4   (OV_DW / 4)       // 7620 uint4 groups
#define TPB    1024
// R5: R2-R4 post-mortem — every 1024-thread variant pinned at a hard 64-VGPR
// budget (VGPR_Count=64 + 440MB scratch each time). Design INSIDE 64:
// ITEMS 32->16 (NCHUNK 4->8) halves accumulator state; plain unrolled item
// loop with in-body scalars (the only shape that never spilled, R1).
// Depth under 64 regs: 16 acc + ~7/item -> ~5-6 items in flight (R1: ~2-3).
#define NCHUNK 8                  // 960 blocks: 960/(4*256)=93.7% slot util
#define BPB    (NB / NCHUNK)      // 16000 bins per block
#define ITEMS  16                 // 16000/1024 = 15.625; last item partial
#define NBJ    (B_ * J_)          // 120
#define NBLK   (NBJ * NCHUNK)     // 960

typedef __fp16 fp16x2 __attribute__((ext_vector_type(2)));

__device__ __forceinline__ unsigned int pkrtz(float lo, float hi) {
    fp16x2 h = __builtin_amdgcn_cvt_pkrtz(lo, hi);  // v_cvt_pkrtz_f16_f32
    return __builtin_bit_cast(unsigned int, h);
}

// f32 dot of two f16 pairs: v_dot2_f32_f16 (f32 accumulate; fewer VALU ops
// and more precise than an hmul2/hfma2 chain rounding products to f16).
__device__ __forceinline__ float fdot2(unsigned int d, unsigned int w, float c) {
#if __has_builtin(__builtin_amdgcn_fdot2)
    return __builtin_amdgcn_fdot2(__builtin_bit_cast(fp16x2, d),
                                  __builtin_bit_cast(fp16x2, w), c, false);
#else
    __half2 p = __hmul2(__builtin_bit_cast(__half2, d),
                        __builtin_bit_cast(__half2, w));
    return c + __low2float(p) + __high2float(p);
#endif
}

// Bilinear weights, padding_mode='zeros' validity folded into clamped 2x2
// window. Camera-mean 1/5 folded into weights.
// addr16 = yc*W + xc (max 30478, fits u16);
// w0pk=(0.2*a0*b0, 0.2*a0*b1) for col xc, w1pk likewise for xc+1 — pair over
// rows (yc, yc+1) matches the overlapping row-pair LDS dword layout.
__device__ __forceinline__ void bilinear_rec(float gx, float gy,
                                             unsigned int& addr,
                                             unsigned int& w0pk,
                                             unsigned int& w1pk) {
    const float ix = (gx + 1.0f) * (0.5f * (W_ - 1));
    const float iy = (gy + 1.0f) * (0.5f * (H_ - 1));
    const float x0f = floorf(ix);
    const float y0f = floorf(iy);
    const float wx1 = ix - x0f, wx0 = 1.0f - wx1;
    const float wy1 = iy - y0f, wy0 = 1.0f - wy1;
    const int x0 = (int)x0f;
    const int y0 = (int)y0f;
    const int xc = min(max(x0, 0), W_ - 2);
    const int yc = min(max(y0, 0), H_ - 2);
    const float vx0 = (x0 >= 0  && x0 <= W_ - 1) ? wx0 : 0.0f;
    const float vx1 = (x0 >= -1 && x0 <= W_ - 2) ? wx1 : 0.0f;
    const float vy0 = (y0 >= 0  && y0 <= H_ - 1) ? wy0 : 0.0f;
    const float vy1 = (y0 >= -1 && y0 <= H_ - 2) ? wy1 : 0.0f;
    const bool xhi = (x0 == W_ - 1);
    const bool xlo = (x0 == -1);
    const bool yhi = (y0 == H_ - 1);
    const bool ylo = (y0 == -1);
    const float a0 = (xhi ? 0.0f : vx0) + (xlo ? vx1 : 0.0f);
    const float a1 = (xhi ? vx0 : 0.0f) + (xlo ? 0.0f : vx1);
    const float b0 = (yhi ? 0.0f : vy0) + (ylo ? vy1 : 0.0f);
    const float b1 = (yhi ? vy0 : 0.0f) + (ylo ? 0.0f : vy1);
    addr = (unsigned int)(yc * W_ + xc);
    w0pk = pkrtz(0.2f * (a0 * b0), 0.2f * (a0 * b1));
    w1pk = pkrtz(0.2f * (a1 * b0), 0.2f * (a1 * b1));
}

__global__ __launch_bounds__(256) void weights_kernel(
    const float* __restrict__ sgrid,          // [NCAM, NB, 2]
    unsigned short* __restrict__ addr16,      // [NCAM*NB]
    uint2* __restrict__ wpk)                  // [NCAM*NB]
{
    const int i = blockIdx.x * 256 + threadIdx.x;
    if (i >= NCAM * NB) return;
    const float2 g = ((const float2*)sgrid)[i];
    unsigned int a, w0, w1;
    bilinear_rec(g.x, g.y, a, w0, w1);
    addr16[i] = (unsigned short)a;
    wpk[i] = make_uint2(w0, w1);
}

// Stage f32 HxW image as overlapping row-pair f16 dwords (121.9 KB).
__device__ __forceinline__ void stage_overlap(const float* __restrict__ img,
                                              unsigned int* s_img, int tid) {
    const float4* __restrict__ src4 = (const float4*)img;  // 60 groups per row
    uint4* dst = (uint4*)s_img;
    for (int gi = tid; gi < OV_G4; gi += TPB) {
        const int y  = gi / 60;
        const int xg = gi - y * 60;
        const float4 t = src4[y * 60 + xg];        // row y
        const float4 b = src4[y * 60 + 60 + xg];   // row y+1
        uint4 d;
        d.x = pkrtz(t.x, b.x);
        d.y = pkrtz(t.y, b.y);
        d.z = pkrtz(t.z, b.z);
        d.w = pkrtz(t.w, b.w);
        dst[gi] = d;
    }
}

// Static LDS (121.9 KB -> 1 block/CU, 16 waves). Attributes request the
// honest occupancy (4 waves/EU); if honored, VGPR budget rises past 64 and
// the scheduler can pipeline deeper — but the kernel FITS in 64 regardless.
__global__
__attribute__((amdgpu_flat_work_group_size(TPB, TPB), amdgpu_waves_per_eu(4, 4)))
void project_kernel(
    const float* __restrict__ hm,             // [B, NCAM, J, H, W]
    const unsigned short* __restrict__ addr16,
    const uint2* __restrict__ wpk,
    float* __restrict__ out)                  // [B, J, NB]
{
    __shared__ unsigned int s_img[OV_DW];     // STATIC: 121920 B
    const int tid   = threadIdx.x;
    // bj-major mapping: same-bj blocks at bids bj+120k; 120%8==0 -> same XCD,
    // so all 8 chunks of a (b,j) share one XCD's L2 for the staged images.
    const int bj    = blockIdx.x % NBJ;
    const int chunk = blockIdx.x / NBJ;
    const int b     = bj / J_;
    const int j     = bj % J_;
    const int bin0  = chunk * BPB;
    // last item: r = 15*1024+tid < 16000  <=>  tid < 640 (wave-uniform)
    const bool tail_ok = (tid < BPB - (ITEMS - 1) * TPB);

    float acc[ITEMS];
#pragma unroll
    for (int it = 0; it < ITEMS; ++it) acc[it] = 0.0f;

    for (int n = 0; n < NCAM; ++n) {
        __syncthreads();          // prev camera's sampling done
        stage_overlap(hm + (((size_t)b * NCAM + n) * J_ + j) * HW_, s_img, tid);
        __syncthreads();
        const unsigned short* __restrict__ ap = addr16 + n * NB + bin0;
        const uint2* __restrict__ wp = wpk + n * NB + bin0;
        // Plain unrolled item loop, in-body scalars (R1 shape: never spilled).
        // Compiler interleaves as many items as the register budget allows.
#pragma unroll
        for (int it = 0; it < ITEMS; ++it) {
            const int r = it * TPB + tid;      // coalesced; it is constant
            unsigned int a;
            uint2 w;
            if (it < ITEMS - 1 || tail_ok) {
                a = ap[r];
                w = wp[r];
            } else {                           // tail: garbage*0 == 0
                a = 0u;
                w = make_uint2(0u, 0u);
            }
            const unsigned int d0 = s_img[a];       // ds_read2_b32:
            const unsigned int d1 = s_img[a + 1u];  // cols xc, xc+1
            acc[it] = fdot2(d1, w.y, fdot2(d0, w.x, acc[it]));
        }
    }

    float* __restrict__ o = out + (size_t)bj * NB + bin0;
#pragma unroll
    for (int it = 0; it < ITEMS; ++it) {
        const int r = it * TPB + tid;
        if (it < ITEMS - 1 || tail_ok)
            o[r] = fminf(fmaxf(acc[it], 0.0f), 1.0f);  // 1/5 in weights
    }
}

// Fallback (tiny ws): R1-style f32-LDS kernel, inline weights. 600 blocks.
#define FB_SMEM   (HW_ * 4)
#define FB_NCHUNK 5
#define FB_BPB    (NB / FB_NCHUNK)   // 25600
#define FB_ITEMS  (FB_BPB / TPB)     // 25
__global__ __launch_bounds__(TPB) void project_fallback(
    const float* __restrict__ hm,
    const float* __restrict__ sgrid,
    float* __restrict__ out)
{
    extern __shared__ float s_f32[];
    const int tid   = threadIdx.x;
    const int bj    = blockIdx.x % NBJ;
    const int chunk = blockIdx.x / NBJ;
    const int b     = bj / J_;
    const int j     = bj % J_;
    const int bin0  = chunk * FB_BPB;

    float acc[FB_ITEMS];
#pragma unroll
    for (int it = 0; it < FB_ITEMS; ++it) acc[it] = 0.0f;

    for (int n = 0; n < NCAM; ++n) {
        __syncthreads();
        const float4* __restrict__ src =
            (const float4*)(hm + (((size_t)b * NCAM + n) * J_ + j) * HW_);
        float4* dst = (float4*)s_f32;
        for (int i = tid; i < HW_ / 4; i += TPB) dst[i] = src[i];
        __syncthreads();
        const float2* __restrict__ g2 = (const float2*)sgrid + n * NB + bin0;
#pragma unroll
        for (int it = 0; it < FB_ITEMS; ++it) {
            const float2 g = g2[it * TPB + tid];
            const float ix = (g.x + 1.0f) * (0.5f * (W_ - 1));
            const float iy = (g.y + 1.0f) * (0.5f * (H_ - 1));
            const float x0f = floorf(ix), y0f = floorf(iy);
            const float wx1 = ix - x0f, wx0 = 1.0f - wx1;
            const float wy1 = iy - y0f, wy0 = 1.0f - wy1;
            const int x0 = (int)x0f, y0 = (int)y0f;
            const int xc = min(max(x0, 0), W_ - 2);
            const int yc = min(max(y0, 0), H_ - 2);
            const float vx0 = (x0 >= 0  && x0 <= W_ - 1) ? wx0 : 0.0f;
            const float vx1 = (x0 >= -1 && x0 <= W_ - 2) ? wx1 : 0.0f;
            const float vy0 = (y0 >= 0  && y0 <= H_ - 1) ? wy0 : 0.0f;
            const float vy1 = (y0 >= -1 && y0 <= H_ - 2) ? wy1 : 0.0f;
            const bool xhi = (x0 == W_ - 1), xlo = (x0 == -1);
            const bool yhi = (y0 == H_ - 1), ylo = (y0 == -1);
            const float a0 = (xhi ? 0.0f : vx0) + (xlo ? vx1 : 0.0f);
            const float a1 = (xhi ? vx0 : 0.0f) + (xlo ? 0.0f : vx1);
            const float b0 = (yhi ? 0.0f : vy0) + (ylo ? vy1 : 0.0f);
            const float b1 = (yhi ? vy0 : 0.0f) + (ylo ? 0.0f : vy1);
            const float* r0 = s_f32 + (yc * W_ + xc);
            acc[it] += b0 * (a0 * r0[0] + a1 * r0[1])
                     + b1 * (a0 * r0[W_] + a1 * r0[W_ + 1]);
        }
    }
    float* __restrict__ o = out + (size_t)bj * NB + bin0;
#pragma unroll
    for (int it = 0; it < FB_ITEMS; ++it)
        o[it * TPB + tid] = fminf(fmaxf(acc[it] * 0.2f, 0.0f), 1.0f);
}

extern "C" void kernel_launch(void* const* d_in, const int* in_sizes, int n_in,
                              void* d_out, int out_size, void* d_ws, size_t ws_size,
                              hipStream_t stream) {
    const float* hm = (const float*)d_in[0];   // [8,5,15,128,240] f32
    const float* sg = (const float*)d_in[1];   // [5,128000,2] f32
    float* out = (float*)d_out;                // [8,15,128000] f32

    (void)hipFuncSetAttribute((const void*)project_fallback,
                              hipFuncAttributeMaxDynamicSharedMemorySize, FB_SMEM);

    const size_t addr_bytes = (size_t)NCAM * NB * sizeof(unsigned short); // 1.28 MB
    const size_t wpk_bytes  = (size_t)NCAM * NB * sizeof(uint2);          // 5.12 MB
    if (ws_size >= addr_bytes + wpk_bytes) {
        unsigned short* addr16 = (unsigned short*)d_ws;
        uint2* wpk = (uint2*)((char*)d_ws + addr_bytes);
        weights_kernel<<<(NCAM * NB + 255) / 256, 256, 0, stream>>>(sg, addr16, wpk);
        project_kernel<<<NBLK, TPB, 0, stream>>>(hm, addr16, wpk, out);
    } else {
        project_fallback<<<NBJ * FB_NCHUNK, TPB, FB_SMEM, stream>>>(hm, sg, out);
    }
}

// Round 6
// 227.032 us; speedup vs baseline: 1.8749x; 1.6513x over previous
//
#include <hip/hip_runtime.h>
#include <hip/hip_fp16.h>

// Problem constants
#define B_     8
#define NCAM   5
#define J_     15
#define H_     128
#define W_     240
#define NB     128000             // bins = 80*80*20
#define HW_    (H_ * W_)          // 30720
// Overlapping row-pair f16 image: dword[y][x] = (f16 v(y,x), f16 v(y+1,x)),
// y in 0..H-2. Any clamped 2x2 window = dwords (yc,xc),(yc,xc+1): ONE
// ds_read2_b32 per sample, all 8B useful.
#define OV_ROWS (H_ - 1)          // 127
#define OV_DW   (OV_ROWS * W_)    // 30480 dwords
#define OV_G4   (OV_DW / 4)       // 7620 uint4 groups
#define TPB    1024
// R6: TPB=1024 budget is HARD 64 VGPRs (R2-R5: every deeper structure
// spilled at exactly 64). Engineer depth INSIDE 64: 16 named accumulators,
// 4 batches x 4 items, nested OPAQUE guards (bpb = runtime arg -> compiler
// cannot fold/merge batches; this is the fence R5 lacked). Peak live ~54.
#define NCHUNK 8                  // 960 blocks
#define BPB    (NB / NCHUNK)      // 16000 bins per block
#define ITEMS  16                 // 16000/1024 = 15.625; item 15 partial
#define NBJ    (B_ * J_)          // 120
#define NBLK   (NBJ * NCHUNK)     // 960

typedef __fp16 fp16x2 __attribute__((ext_vector_type(2)));

__device__ __forceinline__ unsigned int pkrtz(float lo, float hi) {
    fp16x2 h = __builtin_amdgcn_cvt_pkrtz(lo, hi);  // v_cvt_pkrtz_f16_f32
    return __builtin_bit_cast(unsigned int, h);
}

// f32 dot of two f16 pairs: v_dot2_f32_f16 (f32 accumulate).
__device__ __forceinline__ float fdot2(unsigned int d, unsigned int w, float c) {
#if __has_builtin(__builtin_amdgcn_fdot2)
    return __builtin_amdgcn_fdot2(__builtin_bit_cast(fp16x2, d),
                                  __builtin_bit_cast(fp16x2, w), c, false);
#else
    __half2 p = __hmul2(__builtin_bit_cast(__half2, d),
                        __builtin_bit_cast(__half2, w));
    return c + __low2float(p) + __high2float(p);
#endif
}

// Bilinear weights, padding_mode='zeros' validity folded into clamped 2x2
// window. Camera-mean 1/5 folded into weights.
// addr16 = yc*W + xc (max 30478, fits u16);
// w0pk=(0.2*a0*b0, 0.2*a0*b1) for col xc, w1pk likewise for xc+1 — pair over
// rows (yc, yc+1) matches the overlapping row-pair LDS dword layout.
__device__ __forceinline__ void bilinear_rec(float gx, float gy,
                                             unsigned int& addr,
                                             unsigned int& w0pk,
                                             unsigned int& w1pk) {
    const float ix = (gx + 1.0f) * (0.5f * (W_ - 1));
    const float iy = (gy + 1.0f) * (0.5f * (H_ - 1));
    const float x0f = floorf(ix);
    const float y0f = floorf(iy);
    const float wx1 = ix - x0f, wx0 = 1.0f - wx1;
    const float wy1 = iy - y0f, wy0 = 1.0f - wy1;
    const int x0 = (int)x0f;
    const int y0 = (int)y0f;
    const int xc = min(max(x0, 0), W_ - 2);
    const int yc = min(max(y0, 0), H_ - 2);
    const float vx0 = (x0 >= 0  && x0 <= W_ - 1) ? wx0 : 0.0f;
    const float vx1 = (x0 >= -1 && x0 <= W_ - 2) ? wx1 : 0.0f;
    const float vy0 = (y0 >= 0  && y0 <= H_ - 1) ? wy0 : 0.0f;
    const float vy1 = (y0 >= -1 && y0 <= H_ - 2) ? wy1 : 0.0f;
    const bool xhi = (x0 == W_ - 1);
    const bool xlo = (x0 == -1);
    const bool yhi = (y0 == H_ - 1);
    const bool ylo = (y0 == -1);
    const float a0 = (xhi ? 0.0f : vx0) + (xlo ? vx1 : 0.0f);
    const float a1 = (xhi ? vx0 : 0.0f) + (xlo ? 0.0f : vx1);
    const float b0 = (yhi ? 0.0f : vy0) + (ylo ? vy1 : 0.0f);
    const float b1 = (yhi ? vy0 : 0.0f) + (ylo ? 0.0f : vy1);
    addr = (unsigned int)(yc * W_ + xc);
    w0pk = pkrtz(0.2f * (a0 * b0), 0.2f * (a0 * b1));
    w1pk = pkrtz(0.2f * (a1 * b0), 0.2f * (a1 * b1));
}

__global__ __launch_bounds__(256) void weights_kernel(
    const float* __restrict__ sgrid,          // [NCAM, NB, 2]
    unsigned short* __restrict__ addr16,      // [NCAM*NB]
    uint2* __restrict__ wpk)                  // [NCAM*NB]
{
    const int i = blockIdx.x * 256 + threadIdx.x;
    if (i >= NCAM * NB) return;
    const float2 g = ((const float2*)sgrid)[i];
    unsigned int a, w0, w1;
    bilinear_rec(g.x, g.y, a, w0, w1);
    addr16[i] = (unsigned short)a;
    wpk[i] = make_uint2(w0, w1);
}

// Stage f32 HxW image as overlapping row-pair f16 dwords (121.9 KB).
__device__ __forceinline__ void stage_overlap(const float* __restrict__ img,
                                              unsigned int* s_img, int tid) {
    const float4* __restrict__ src4 = (const float4*)img;  // 60 groups per row
    uint4* dst = (uint4*)s_img;
    for (int gi = tid; gi < OV_G4; gi += TPB) {
        const int y  = gi / 60;
        const int xg = gi - y * 60;
        const float4 t = src4[y * 60 + xg];        // row y
        const float4 b = src4[y * 60 + 60 + xg];   // row y+1
        uint4 d;
        d.x = pkrtz(t.x, b.x);
        d.y = pkrtz(t.y, b.y);
        d.z = pkrtz(t.z, b.z);
        d.w = pkrtz(t.w, b.w);
        dst[gi] = d;
    }
}

// ---- named-scalar batch macros (no arrays anywhere) ----
#define LOADI(IT) \
    const unsigned int a##IT = ap[(IT) * TPB + tid]; \
    const uint2        w##IT = wp[(IT) * TPB + tid];
// tail item: clamped in-bounds load + zero-select (no OOB, no extra branch)
#define LOADI_T(IT) \
    const int rt##IT = min((IT) * TPB + tid, BPB - 1); \
    const unsigned int a##IT = ap[rt##IT]; \
    const uint2        wt##IT = wp[rt##IT]; \
    const uint2        w##IT = tail_ok ? wt##IT : make_uint2(0u, 0u);
#define DSI(IT) \
    const unsigned int p##IT = s_img[a##IT]; \
    const unsigned int q##IT = s_img[a##IT + 1u];
#define DOTI(IT) \
    acc##IT = fdot2(q##IT, w##IT.y, fdot2(p##IT, w##IT.x, acc##IT));
#define OUTI(IT) \
    if ((IT) * TPB + tid < BPB) \
        o[(IT) * TPB + tid] = fminf(fmaxf(acc##IT, 0.0f), 1.0f);

// Static LDS 121.9 KB -> 1 block/CU, 16 waves (4/EU). launch_bounds(TPB,4):
// known-good 64-VGPR config (R1). Kernel engineered to peak ~54 live regs.
__global__ __launch_bounds__(TPB, 4) void project_kernel(
    const float* __restrict__ hm,             // [B, NCAM, J, H, W]
    const unsigned short* __restrict__ addr16,
    const uint2* __restrict__ wpk,
    float* __restrict__ out,                  // [B, J, NB]
    int bpb)                                  // == BPB; runtime-opaque fence
{
    __shared__ unsigned int s_img[OV_DW];     // STATIC: 121920 B
    const int tid   = threadIdx.x;
    // bj-major mapping: same-bj blocks at bids bj+120k; 120%8==0 -> same XCD,
    // so all 8 chunks of a (b,j) share one XCD's L2 for the staged images.
    const int bj    = blockIdx.x % NBJ;
    const int chunk = blockIdx.x / NBJ;
    const int b     = bj / J_;
    const int j     = bj % J_;
    const int bin0  = chunk * BPB;
    // item 15: r = 15*1024+tid < 16000  <=>  tid < 640
    const bool tail_ok = (tid < BPB - (ITEMS - 1) * TPB);

    float acc0 = 0.f, acc1 = 0.f, acc2 = 0.f, acc3 = 0.f;
    float acc4 = 0.f, acc5 = 0.f, acc6 = 0.f, acc7 = 0.f;
    float acc8 = 0.f, acc9 = 0.f, acc10 = 0.f, acc11 = 0.f;
    float acc12 = 0.f, acc13 = 0.f, acc14 = 0.f, acc15 = 0.f;

    for (int n = 0; n < NCAM; ++n) {
        const unsigned short* __restrict__ ap = addr16 + n * NB + bin0;
        const uint2* __restrict__ wp = wpk + n * NB + bin0;
        // Batch 0's weight loads issue BEFORE staging: ~2.5k-cycle cover for
        // the ~400cy L2/L3 latency (loads are global, independent of LDS).
        LOADI(0) LOADI(1) LOADI(2) LOADI(3)
        __syncthreads();          // prev camera's sampling done
        stage_overlap(hm + (((size_t)b * NCAM + n) * J_ + j) * HW_, s_img, tid);
        __syncthreads();
        // Nested OPAQUE guards (bpb runtime; every guard true at runtime):
        // pure scheduling fences — batches cannot be merged/hoisted, so live
        // set stays ~54 regs. Pipeline: batch g = {issue g+1 loads | ds(g)
        // (vmcnt wait leaves g+1 in flight) | dot(g)}.
        if (tid < bpb) {
            LOADI(4) LOADI(5) LOADI(6) LOADI(7)
            DSI(0) DSI(1) DSI(2) DSI(3)
            DOTI(0) DOTI(1) DOTI(2) DOTI(3)
            if (4 * TPB + tid < bpb) {
                LOADI(8) LOADI(9) LOADI(10) LOADI(11)
                DSI(4) DSI(5) DSI(6) DSI(7)
                DOTI(4) DOTI(5) DOTI(6) DOTI(7)
                if (8 * TPB + tid < bpb) {
                    LOADI(12) LOADI(13) LOADI(14) LOADI_T(15)
                    DSI(8) DSI(9) DSI(10) DSI(11)
                    DOTI(8) DOTI(9) DOTI(10) DOTI(11)
                    if (12 * TPB + tid < bpb) {
                        DSI(12) DSI(13) DSI(14) DSI(15)
                        DOTI(12) DOTI(13) DOTI(14) DOTI(15)
                    }
                }
            }
        }
    }

    float* __restrict__ o = out + (size_t)bj * NB + bin0;
    OUTI(0) OUTI(1) OUTI(2) OUTI(3) OUTI(4) OUTI(5) OUTI(6) OUTI(7)
    OUTI(8) OUTI(9) OUTI(10) OUTI(11) OUTI(12) OUTI(13) OUTI(14) OUTI(15)
}

// Fallback (tiny ws): R1-style f32-LDS kernel, inline weights. 600 blocks.
#define FB_SMEM   (HW_ * 4)
#define FB_NCHUNK 5
#define FB_BPB    (NB / FB_NCHUNK)   // 25600
#define FB_ITEMS  (FB_BPB / TPB)     // 25
__global__ __launch_bounds__(TPB) void project_fallback(
    const float* __restrict__ hm,
    const float* __restrict__ sgrid,
    float* __restrict__ out)
{
    extern __shared__ float s_f32[];
    const int tid   = threadIdx.x;
    const int bj    = blockIdx.x % NBJ;
    const int chunk = blockIdx.x / NBJ;
    const int b     = bj / J_;
    const int j     = bj % J_;
    const int bin0  = chunk * FB_BPB;

    float acc[FB_ITEMS];
#pragma unroll
    for (int it = 0; it < FB_ITEMS; ++it) acc[it] = 0.0f;

    for (int n = 0; n < NCAM; ++n) {
        __syncthreads();
        const float4* __restrict__ src =
            (const float4*)(hm + (((size_t)b * NCAM + n) * J_ + j) * HW_);
        float4* dst = (float4*)s_f32;
        for (int i = tid; i < HW_ / 4; i += TPB) dst[i] = src[i];
        __syncthreads();
        const float2* __restrict__ g2 = (const float2*)sgrid + n * NB + bin0;
#pragma unroll
        for (int it = 0; it < FB_ITEMS; ++it) {
            const float2 g = g2[it * TPB + tid];
            const float ix = (g.x + 1.0f) * (0.5f * (W_ - 1));
            const float iy = (g.y + 1.0f) * (0.5f * (H_ - 1));
            const float x0f = floorf(ix), y0f = floorf(iy);
            const float wx1 = ix - x0f, wx0 = 1.0f - wx1;
            const float wy1 = iy - y0f, wy0 = 1.0f - wy1;
            const int x0 = (int)x0f, y0 = (int)y0f;
            const int xc = min(max(x0, 0), W_ - 2);
            const int yc = min(max(y0, 0), H_ - 2);
            const float vx0 = (x0 >= 0  && x0 <= W_ - 1) ? wx0 : 0.0f;
            const float vx1 = (x0 >= -1 && x0 <= W_ - 2) ? wx1 : 0.0f;
            const float vy0 = (y0 >= 0  && y0 <= H_ - 1) ? wy0 : 0.0f;
            const float vy1 = (y0 >= -1 && y0 <= H_ - 2) ? wy1 : 0.0f;
            const bool xhi = (x0 == W_ - 1), xlo = (x0 == -1);
            const bool yhi = (y0 == H_ - 1), ylo = (y0 == -1);
            const float a0 = (xhi ? 0.0f : vx0) + (xlo ? vx1 : 0.0f);
            const float a1 = (xhi ? vx0 : 0.0f) + (xlo ? 0.0f : vx1);
            const float b0 = (yhi ? 0.0f : vy0) + (ylo ? vy1 : 0.0f);
            const float b1 = (yhi ? vy0 : 0.0f) + (ylo ? 0.0f : vy1);
            const float* r0 = s_f32 + (yc * W_ + xc);
            acc[it] += b0 * (a0 * r0[0] + a1 * r0[1])
                     + b1 * (a0 * r0[W_] + a1 * r0[W_ + 1]);
        }
    }
    float* __restrict__ o = out + (size_t)bj * NB + bin0;
#pragma unroll
    for (int it = 0; it < FB_ITEMS; ++it)
        o[it * TPB + tid] = fminf(fmaxf(acc[it] * 0.2f, 0.0f), 1.0f);
}

extern "C" void kernel_launch(void* const* d_in, const int* in_sizes, int n_in,
                              void* d_out, int out_size, void* d_ws, size_t ws_size,
                              hipStream_t stream) {
    const float* hm = (const float*)d_in[0];   // [8,5,15,128,240] f32
    const float* sg = (const float*)d_in[1];   // [5,128000,2] f32
    float* out = (float*)d_out;                // [8,15,128000] f32

    (void)hipFuncSetAttribute((const void*)project_fallback,
                              hipFuncAttributeMaxDynamicSharedMemorySize, FB_SMEM);

    const size_t addr_bytes = (size_t)NCAM * NB * sizeof(unsigned short); // 1.28 MB
    const size_t wpk_bytes  = (size_t)NCAM * NB * sizeof(uint2);          // 5.12 MB
    if (ws_size >= addr_bytes + wpk_bytes) {
        unsigned short* addr16 = (unsigned short*)d_ws;
        uint2* wpk = (uint2*)((char*)d_ws + addr_bytes);
        weights_kernel<<<(NCAM * NB + 255) / 256, 256, 0, stream>>>(sg, addr16, wpk);
        project_kernel<<<NBLK, TPB, 0, stream>>>(hm, addr16, wpk, out, BPB);
    } else {
        project_fallback<<<NBJ * FB_NCHUNK, TPB, FB_SMEM, stream>>>(hm, sg, out);
    }
}

// Round 7
// 211.399 us; speedup vs baseline: 2.0136x; 1.0740x over previous
//
#include <hip/hip_runtime.h>
#include <hip/hip_fp16.h>

// Problem constants
#define B_     8
#define NCAM   5
#define J_     15
#define H_     128
#define W_     240
#define NB     128000             // bins = 80*80*20
#define HW_    (H_ * W_)          // 30720
// R7: X-pair f16 layout: dword[y][xp] = (f16 v(y,2xp), f16 v(y,2xp+1)),
// y in 0..127, xp in 0..119. 15360 dwords = 61.4 KB per image:
//  - staging reads each f32 ONCE (120 KB vs overlap-pair's 244 KB)
//  - TWO buffers fit LDS (122.9 KB) -> double-buffer: stage cam n+1
//    interleaved with sampling cam n; ONE barrier per camera.
// Sample: ds_read2(0,120) for rows yc,yc+1 at col-pair xp; odd xc lanes
// additionally read xp+1 (divergent branch, ~half lanes); v_perm splices
// the (xc, xc+1) f16 pair per row.
#define XP_DW   15360             // dwords per image buffer
#define XP_PAD  15368             // +8 dwords pad, keeps buf1 16B-aligned
#define XP_G4   (XP_DW / 4)       // 3840 uint4 stage units
#define TPB    1024
#define NCHUNK 8                  // 960 blocks
#define BPB    (NB / NCHUNK)      // 16000 bins per block
#define ITEMS  16                 // item 15 partial (tid < 640)
#define NBJ    (B_ * J_)          // 120
#define NBLK   (NBJ * NCHUNK)     // 960

typedef __fp16 fp16x2 __attribute__((ext_vector_type(2)));

__device__ __forceinline__ unsigned int pkrtz(float lo, float hi) {
    fp16x2 h = __builtin_amdgcn_cvt_pkrtz(lo, hi);  // v_cvt_pkrtz_f16_f32
    return __builtin_bit_cast(unsigned int, h);
}

// f32 dot of two f16 pairs: v_dot2_f32_f16 (f32 accumulate).
__device__ __forceinline__ float fdot2(unsigned int d, unsigned int w, float c) {
#if __has_builtin(__builtin_amdgcn_fdot2)
    return __builtin_amdgcn_fdot2(__builtin_bit_cast(fp16x2, d),
                                  __builtin_bit_cast(fp16x2, w), c, false);
#else
    __half2 p = __hmul2(__builtin_bit_cast(__half2, d),
                        __builtin_bit_cast(__half2, w));
    return c + __low2float(p) + __high2float(p);
#endif
}

// Bilinear weights, padding_mode='zeros' validity folded into clamped 2x2
// window (math identical to validated R0-R6; only PACKING changed for the
// X-pair layout). Camera-mean 1/5 folded in.
// addr16 = (yc*120 + (xc>>1)) | ((xc&1) << 14)   (max 15239 < 2^14, fits)
// w0pk = (0.2*a0*b0, 0.2*a1*b0)  -- row yc, cols (xc, xc+1)
// w1pk = (0.2*a0*b1, 0.2*a1*b1)  -- row yc+1
__device__ __forceinline__ void bilinear_rec(float gx, float gy,
                                             unsigned int& addr,
                                             unsigned int& w0pk,
                                             unsigned int& w1pk) {
    const float ix = (gx + 1.0f) * (0.5f * (W_ - 1));
    const float iy = (gy + 1.0f) * (0.5f * (H_ - 1));
    const float x0f = floorf(ix);
    const float y0f = floorf(iy);
    const float wx1 = ix - x0f, wx0 = 1.0f - wx1;
    const float wy1 = iy - y0f, wy0 = 1.0f - wy1;
    const int x0 = (int)x0f;
    const int y0 = (int)y0f;
    const int xc = min(max(x0, 0), W_ - 2);
    const int yc = min(max(y0, 0), H_ - 2);
    const float vx0 = (x0 >= 0  && x0 <= W_ - 1) ? wx0 : 0.0f;
    const float vx1 = (x0 >= -1 && x0 <= W_ - 2) ? wx1 : 0.0f;
    const float vy0 = (y0 >= 0  && y0 <= H_ - 1) ? wy0 : 0.0f;
    const float vy1 = (y0 >= -1 && y0 <= H_ - 2) ? wy1 : 0.0f;
    const bool xhi = (x0 == W_ - 1);
    const bool xlo = (x0 == -1);
    const bool yhi = (y0 == H_ - 1);
    const bool ylo = (y0 == -1);
    const float a0 = (xhi ? 0.0f : vx0) + (xlo ? vx1 : 0.0f);
    const float a1 = (xhi ? vx0 : 0.0f) + (xlo ? 0.0f : vx1);
    const float b0 = (yhi ? 0.0f : vy0) + (ylo ? vy1 : 0.0f);
    const float b1 = (yhi ? vy0 : 0.0f) + (ylo ? 0.0f : vy1);
    const int xp = xc >> 1;
    const int p  = xc & 1;
    addr = (unsigned int)(yc * 120 + xp) | ((unsigned int)p << 14);
    w0pk = pkrtz(0.2f * (a0 * b0), 0.2f * (a1 * b0));
    w1pk = pkrtz(0.2f * (a0 * b1), 0.2f * (a1 * b1));
}

__global__ __launch_bounds__(256) void weights_kernel(
    const float* __restrict__ sgrid,          // [NCAM, NB, 2]
    unsigned short* __restrict__ addr16,      // [NCAM*NB]
    uint2* __restrict__ wpk)                  // [NCAM*NB]
{
    const int i = blockIdx.x * 256 + threadIdx.x;
    if (i >= NCAM * NB) return;
    const float2 g = ((const float2*)sgrid)[i];
    unsigned int a, w0, w1;
    bilinear_rec(g.x, g.y, a, w0, w1);
    addr16[i] = (unsigned short)a;
    wpk[i] = make_uint2(w0, w1);
}

// ---- named-scalar macros (no arrays; all indices literal) ----
#define LOADI(IT) \
    const unsigned int a##IT = ap[(IT) * TPB + tid]; \
    const uint2        w##IT = wp[(IT) * TPB + tid];
// tail item: clamped in-bounds load + zero weights (garbage*0 == 0)
#define LOADI_T(IT) \
    const int rt##IT = min((IT) * TPB + tid, BPB - 1); \
    const unsigned int a##IT = ap[rt##IT]; \
    const uint2        wt##IT = wp[rt##IT]; \
    const uint2        w##IT = tail_ok ? wt##IT : make_uint2(0u, 0u);
// X-pair LDS fetch: always rows yc,yc+1 at xp (one ds_read2 0/120);
// odd-xc lanes also need xp+1 (divergent branch ~half the lanes).
#define DSI(IT) \
    const unsigned int pa##IT = a##IT & 0x3FFFu; \
    const unsigned int d00_##IT = cbuf[pa##IT]; \
    const unsigned int d10_##IT = cbuf[pa##IT + 120u]; \
    unsigned int d01_##IT = 0u, d11_##IT = 0u; \
    if (a##IT >> 14) { d01_##IT = cbuf[pa##IT + 1u]; \
                       d11_##IT = cbuf[pa##IT + 121u]; }
// splice (xc, xc+1) pair per row: even sel = passthrough d00/d10.
#define DOTI(IT) { \
    const unsigned int sel##IT = 0x03020100u + (a##IT >> 14) * 0x02020202u; \
    const unsigned int r0##IT = __builtin_amdgcn_perm(d01_##IT, d00_##IT, sel##IT); \
    const unsigned int r1##IT = __builtin_amdgcn_perm(d11_##IT, d10_##IT, sel##IT); \
    acc##IT = fdot2(r1##IT, w##IT.y, fdot2(r0##IT, w##IT.x, acc##IT)); }
// one staging unit: 2 float4 -> 4 x-pair dwords -> ds_write_b128 into nxt buf
#define STAGE_UNIT(K) \
    if (stage_on && ((K) * TPB + tid < XP_G4)) { \
        const int gi##K = (K) * TPB + tid; \
        const int row##K = gi##K / 30; \
        const int xg##K = gi##K - row##K * 30; \
        const float4 t0##K = src4[row##K * 60 + 2 * xg##K]; \
        const float4 t1##K = src4[row##K * 60 + 2 * xg##K + 1]; \
        nxt4[row##K * 30 + xg##K] = \
            make_uint4(pkrtz(t0##K.x, t0##K.y), pkrtz(t0##K.z, t0##K.w), \
                       pkrtz(t1##K.x, t1##K.y), pkrtz(t1##K.z, t1##K.w)); \
    }
#define OUTI(IT) \
    if ((IT) * TPB + tid < BPB) \
        o[(IT) * TPB + tid] = fminf(fmaxf(acc##IT, 0.0f), 1.0f);

// Static LDS 122.9 KB -> 1 block/CU, 16 waves. Fence levels (opaque bpb
// guards, R6-proven) keep live set ~56 < the hard 64-VGPR budget.
__global__ __launch_bounds__(TPB, 4) void project_kernel(
    const float* __restrict__ hm,             // [B, NCAM, J, H, W]
    const unsigned short* __restrict__ addr16,
    const uint2* __restrict__ wpk,
    float* __restrict__ out,                  // [B, J, NB]
    int bpb)                                  // == BPB; runtime-opaque fence
{
    __shared__ __align__(16) unsigned int s_img[2][XP_PAD];  // 122944 B
    const int tid   = threadIdx.x;
    // bj-major mapping: same-bj blocks at bids bj+120k; 120%8==0 -> same XCD,
    // so all 8 chunks of a (b,j) share one XCD's L2 for the staged images.
    const int bj    = blockIdx.x % NBJ;
    const int chunk = blockIdx.x / NBJ;
    const int b     = bj / J_;
    const int j     = bj % J_;
    const int bin0  = chunk * BPB;
    const bool tail_ok = (tid < BPB - (ITEMS - 1) * TPB);   // tid < 640

    float acc0 = 0.f, acc1 = 0.f, acc2 = 0.f, acc3 = 0.f;
    float acc4 = 0.f, acc5 = 0.f, acc6 = 0.f, acc7 = 0.f;
    float acc8 = 0.f, acc9 = 0.f, acc10 = 0.f, acc11 = 0.f;
    float acc12 = 0.f, acc13 = 0.f, acc14 = 0.f, acc15 = 0.f;

    // Prologue: stage camera 0 into buf0 (serial; only place that's serial).
    {
        const float4* __restrict__ s0 =
            (const float4*)(hm + (((size_t)b * NCAM + 0) * J_ + j) * HW_);
        uint4* __restrict__ d0 = (uint4*)(&s_img[0][0]);
        for (int gi = tid; gi < XP_G4; gi += TPB) {
            const int row = gi / 30;
            const int xg = gi - row * 30;
            const float4 t0 = s0[row * 60 + 2 * xg];
            const float4 t1 = s0[row * 60 + 2 * xg + 1];
            d0[row * 30 + xg] =
                make_uint4(pkrtz(t0.x, t0.y), pkrtz(t0.z, t0.w),
                           pkrtz(t1.x, t1.y), pkrtz(t1.z, t1.w));
        }
    }
    __syncthreads();

    for (int n = 0; n < NCAM; ++n) {
        const unsigned short* __restrict__ ap = addr16 + n * NB + bin0;
        const uint2* __restrict__ wp = wpk + n * NB + bin0;
        const unsigned int* __restrict__ cbuf = &s_img[n & 1][0];
        uint4* __restrict__ nxt4 = (uint4*)(&s_img[(n + 1) & 1][0]);
        const bool stage_on = (n < NCAM - 1);
        const int np = stage_on ? n + 1 : n;
        const float4* __restrict__ src4 =
            (const float4*)(hm + (((size_t)b * NCAM + np) * J_ + j) * HW_);

        LOADI(0) LOADI(1) LOADI(2) LOADI(3)
        // Fence levels (all guards true at runtime; bpb is opaque):
        // sample cam n from cbuf || stage cam n+1 into nxt4, no serial phase.
        if (tid < bpb) {                                       // L0
            LOADI(4) LOADI(5) LOADI(6) LOADI(7)
            STAGE_UNIT(0)
            if (1 * TPB + tid < bpb) {                         // L1
                DSI(0) DSI(1) DOTI(0) DOTI(1)
                DSI(2) DSI(3) DOTI(2) DOTI(3)
                if (2 * TPB + tid < bpb) {                     // L2
                    LOADI(8) LOADI(9) LOADI(10) LOADI(11)
                    STAGE_UNIT(1)
                    if (3 * TPB + tid < bpb) {                 // L3
                        DSI(4) DSI(5) DOTI(4) DOTI(5)
                        DSI(6) DSI(7) DOTI(6) DOTI(7)
                        if (4 * TPB + tid < bpb) {             // L4
                            LOADI(12) LOADI(13) LOADI(14) LOADI_T(15)
                            STAGE_UNIT(2)
                            if (5 * TPB + tid < bpb) {         // L5
                                DSI(8) DSI(9) DOTI(8) DOTI(9)
                                DSI(10) DSI(11) DOTI(10) DOTI(11)
                                if (6 * TPB + tid < bpb) {     // L6
                                    STAGE_UNIT(3)
                                    if (7 * TPB + tid < bpb) { // L7
                                        DSI(12) DSI(13) DOTI(12) DOTI(13)
                                        DSI(14) DSI(15) DOTI(14) DOTI(15)
                                    }
                                }
                            }
                        }
                    }
                }
            }
        }
        __syncthreads();   // cam n reads done; cam n+1 buffer complete
    }

    float* __restrict__ o = out + (size_t)bj * NB + bin0;
    OUTI(0) OUTI(1) OUTI(2) OUTI(3) OUTI(4) OUTI(5) OUTI(6) OUTI(7)
    OUTI(8) OUTI(9) OUTI(10) OUTI(11) OUTI(12) OUTI(13) OUTI(14) OUTI(15)
}

// Fallback (tiny ws): R1-style f32-LDS kernel, inline weights. 600 blocks.
#define FB_SMEM   (HW_ * 4)
#define FB_NCHUNK 5
#define FB_BPB    (NB / FB_NCHUNK)   // 25600
#define FB_ITEMS  (FB_BPB / TPB)     // 25
__global__ __launch_bounds__(TPB) void project_fallback(
    const float* __restrict__ hm,
    const float* __restrict__ sgrid,
    float* __restrict__ out)
{
    extern __shared__ float s_f32[];
    const int tid   = threadIdx.x;
    const int bj    = blockIdx.x % NBJ;
    const int chunk = blockIdx.x / NBJ;
    const int b     = bj / J_;
    const int j     = bj % J_;
    const int bin0  = chunk * FB_BPB;

    float acc[FB_ITEMS];
#pragma unroll
    for (int it = 0; it < FB_ITEMS; ++it) acc[it] = 0.0f;

    for (int n = 0; n < NCAM; ++n) {
        __syncthreads();
        const float4* __restrict__ src =
            (const float4*)(hm + (((size_t)b * NCAM + n) * J_ + j) * HW_);
        float4* dst = (float4*)s_f32;
        for (int i = tid; i < HW_ / 4; i += TPB) dst[i] = src[i];
        __syncthreads();
        const float2* __restrict__ g2 = (const float2*)sgrid + n * NB + bin0;
#pragma unroll
        for (int it = 0; it < FB_ITEMS; ++it) {
            const float2 g = g2[it * TPB + tid];
            const float ix = (g.x + 1.0f) * (0.5f * (W_ - 1));
            const float iy = (g.y + 1.0f) * (0.5f * (H_ - 1));
            const float x0f = floorf(ix), y0f = floorf(iy);
            const float wx1 = ix - x0f, wx0 = 1.0f - wx1;
            const float wy1 = iy - y0f, wy0 = 1.0f - wy1;
            const int x0 = (int)x0f, y0 = (int)y0f;
            const int xc = min(max(x0, 0), W_ - 2);
            const int yc = min(max(y0, 0), H_ - 2);
            const float vx0 = (x0 >= 0  && x0 <= W_ - 1) ? wx0 : 0.0f;
            const float vx1 = (x0 >= -1 && x0 <= W_ - 2) ? wx1 : 0.0f;
            const float vy0 = (y0 >= 0  && y0 <= H_ - 1) ? wy0 : 0.0f;
            const float vy1 = (y0 >= -1 && y0 <= H_ - 2) ? wy1 : 0.0f;
            const bool xhi = (x0 == W_ - 1), xlo = (x0 == -1);
            const bool yhi = (y0 == H_ - 1), ylo = (y0 == -1);
            const float a0 = (xhi ? 0.0f : vx0) + (xlo ? vx1 : 0.0f);
            const float a1 = (xhi ? vx0 : 0.0f) + (xlo ? 0.0f : vx1);
            const float b0 = (yhi ? 0.0f : vy0) + (ylo ? vy1 : 0.0f);
            const float b1 = (yhi ? vy0 : 0.0f) + (ylo ? 0.0f : vy1);
            const float* r0 = s_f32 + (yc * W_ + xc);
            acc[it] += b0 * (a0 * r0[0] + a1 * r0[1])
                     + b1 * (a0 * r0[W_] + a1 * r0[W_ + 1]);
        }
    }
    float* __restrict__ o = out + (size_t)bj * NB + bin0;
#pragma unroll
    for (int it = 0; it < FB_ITEMS; ++it)
        o[it * TPB + tid] = fminf(fmaxf(acc[it] * 0.2f, 0.0f), 1.0f);
}

extern "C" void kernel_launch(void* const* d_in, const int* in_sizes, int n_in,
                              void* d_out, int out_size, void* d_ws, size_t ws_size,
                              hipStream_t stream) {
    const float* hm = (const float*)d_in[0];   // [8,5,15,128,240] f32
    const float* sg = (const float*)d_in[1];   // [5,128000,2] f32
    float* out = (float*)d_out;                // [8,15,128000] f32

    (void)hipFuncSetAttribute((const void*)project_fallback,
                              hipFuncAttributeMaxDynamicSharedMemorySize, FB_SMEM);

    const size_t addr_bytes = (size_t)NCAM * NB * sizeof(unsigned short); // 1.28 MB
    const size_t wpk_bytes  = (size_t)NCAM * NB * sizeof(uint2);          // 5.12 MB
    if (ws_size >= addr_bytes + wpk_bytes) {
        unsigned short* addr16 = (unsigned short*)d_ws;
        uint2* wpk = (uint2*)((char*)d_ws + addr_bytes);
        weights_kernel<<<(NCAM * NB + 255) / 256, 256, 0, stream>>>(sg, addr16, wpk);
        project_kernel<<<NBLK, TPB, 0, stream>>>(hm, addr16, wpk, out, BPB);
    } else {
        project_fallback<<<NBJ * FB_NCHUNK, TPB, FB_SMEM, stream>>>(hm, sg, out);
    }
}